// Round 7
// baseline (494.527 us; speedup 1.0000x reference)
//
#include <hip/hip_runtime.h>
#include <hip/hip_bf16.h>

#define B_ 4
#define S_ 4096
#define D_ 1024
#define NT_ 32        // S_/128
#define PAIRS_ 528    // NT_*(NT_+1)/2 lower-triangle tile pairs

typedef __attribute__((ext_vector_type(8))) short short8;
typedef __attribute__((ext_vector_type(4))) float f32x4;

__device__ __forceinline__ unsigned short f2bf(float f) {
    union { float f; unsigned u; } v; v.f = f;
    unsigned u = v.u;
    return (unsigned short)((u + 0x7fffu + ((u >> 16) & 1u)) >> 16);
}

// async global->LDS, 16B per lane. LDS dst is wave-uniform base + lane*16.
__device__ __forceinline__ void gld_lds16(const unsigned short* g, unsigned short* l) {
    __builtin_amdgcn_global_load_lds((const __attribute__((address_space(1))) void*)g,
                                     (__attribute__((address_space(3))) void*)l, 16, 0, 0);
}

#define LGKM0 asm volatile("s_waitcnt lgkmcnt(0)" ::: "memory")
#define VM0   asm volatile("s_waitcnt vmcnt(0)" ::: "memory")
#define VM4   asm volatile("s_waitcnt vmcnt(4)" ::: "memory")
#define VM6   asm volatile("s_waitcnt vmcnt(6)" ::: "memory")
#define BAR   __builtin_amdgcn_s_barrier()
#define SB0   __builtin_amdgcn_sched_barrier(0)

// ---------------------------------------------------------------------------
// prep_x: fp32 x -> bf16 xb
// ---------------------------------------------------------------------------
__global__ __launch_bounds__(256) void prep_x(const float* __restrict__ x,
                                              unsigned short* __restrict__ xb) {
    size_t i = ((size_t)blockIdx.x * 256 + threadIdx.x) * 8;
    float4 a = *(const float4*)&x[i];
    float4 b = *(const float4*)&x[i + 4];
    unsigned u0 = (unsigned)f2bf(a.x) | ((unsigned)f2bf(a.y) << 16);
    unsigned u1 = (unsigned)f2bf(a.z) | ((unsigned)f2bf(a.w) << 16);
    unsigned u2 = (unsigned)f2bf(b.x) | ((unsigned)f2bf(b.y) << 16);
    unsigned u3 = (unsigned)f2bf(b.z) | ((unsigned)f2bf(b.w) << 16);
    uint4 val; val.x = u0; val.y = u1; val.z = u2; val.w = u3;
    *(uint4*)&xb[i] = val;
}

// ---------------------------------------------------------------------------
// prep_w: W[k][n] fp32 -> Wt[n][k] bf16
// ---------------------------------------------------------------------------
__global__ __launch_bounds__(256) void prep_w(const float* __restrict__ Wq,
                                              const float* __restrict__ Wk,
                                              const float* __restrict__ Wv,
                                              unsigned short* __restrict__ Wt) {
    __shared__ float ls[64 * 65];
    const int z = blockIdx.z;
    const float* __restrict__ W = (z == 0) ? Wq : (z == 1) ? Wk : Wv;
    unsigned short* __restrict__ Wtz = Wt + (size_t)z * D_ * D_;
    const int k0 = blockIdx.y * 64, n0 = blockIdx.x * 64;
    const int tid = threadIdx.x;
    #pragma unroll
    for (int i = 0; i < 16; ++i) {
        int lin = i * 256 + tid, r = lin >> 6, c = lin & 63;
        ls[r * 65 + c] = W[(size_t)(k0 + r) * D_ + n0 + c];
    }
    __syncthreads();
    #pragma unroll
    for (int i = 0; i < 16; ++i) {
        int lin = i * 256 + tid, r = lin >> 6, c = lin & 63;
        Wtz[(size_t)(n0 + r) * D_ + k0 + c] = f2bf(ls[c * 65 + r]);
    }
}

// ---------------------------------------------------------------------------
// qkv_gemm: Y = xb @ Wt_z^T.  REVERTED to round-4 structure (best measured
// 108.4us): 256x256 tile, BK=64, 2 LDS buffers (128 KB), 8 waves (2x4),
// source-swizzled staging + swizzled ds_read, single barrier per K-tile,
// free-run body (compiler fine-grained lgkmcnt), B fragments fully resident.
// z==2 writes Vt directly via per-wave LDS transpose epilogue.
// ---------------------------------------------------------------------------
__global__ __launch_bounds__(512, 2) void qkv_gemm(
    const unsigned short* __restrict__ xb, const unsigned short* __restrict__ Wt,
    unsigned short* __restrict__ Q, unsigned short* __restrict__ K,
    unsigned short* __restrict__ Vt)
{
    __shared__ __align__(16) unsigned short ls[65536];   // 128 KiB
    unsigned short* const lsA = ls;            // 2 x 16384
    unsigned short* const lsB = ls + 32768;    // 2 x 16384

    const int z = blockIdx.z;
    const float scale = (z == 0) ? 0.03125f : 1.0f;

    const int lin = blockIdx.x;                       // 0..255
    const int wg = (lin & 7) * 32 + (lin >> 3);       // XCD-contiguous
    const int m0 = (wg >> 2) * 256, n0 = (wg & 3) * 256;

    const int tid = threadIdx.x, lane = tid & 63, w = tid >> 6;
    const int wm = w >> 2, wn = w & 3;                // 2 x 4 wave grid
    const int quad = lane >> 4, ln = lane & 15;

    const unsigned short* Ab = xb + (size_t)m0 * D_;
    const unsigned short* Bb = Wt + (size_t)z * D_ * D_ + (size_t)n0 * D_;

#define STAGE_HALF(gbase, ldsbase)                                              \
    {                                                                           \
        _Pragma("unroll")                                                       \
        for (int i_ = 0; i_ < 2; ++i_) {                                        \
            int g_ = tid + i_ * 512;                                            \
            int r_ = g_ >> 3;                                                   \
            int cg_ = (g_ & 7) ^ (r_ & 7);                                      \
            gld_lds16((gbase) + (size_t)r_ * D_ + cg_ * 8, (ldsbase) + g_ * 8); \
        }                                                                       \
    }
#define STAGE(kt, h)                                                                   \
    {                                                                                  \
        if ((h) < 2) { STAGE_HALF(Ab + (size_t)((h) * 128) * D_ + (kt) * 64,           \
                                  &lsA[(((kt) & 1) * 2 + (h)) * 8192]) }               \
        else         { STAGE_HALF(Bb + (size_t)(((h) - 2) * 128) * D_ + (kt) * 64,     \
                                  &lsB[(((kt) & 1) * 2 + ((h) - 2)) * 8192]) }         \
    }

    const unsigned short* As;
    const unsigned short* Bs;
    short8 a[4][2], b[4][2];
    f32x4 acc[8][4] = {};

#define LDA(mh)                                                                        \
    {                                                                                  \
        _Pragma("unroll")                                                              \
        for (int mf_ = 0; mf_ < 4; ++mf_) {                                            \
            _Pragma("unroll")                                                          \
            for (int ks_ = 0; ks_ < 2; ++ks_) {                                        \
                int r_ = wm * 128 + ((mh) * 4 + mf_) * 16 + ln;                        \
                int cg_ = ks_ * 4 + quad;                                              \
                a[mf_][ks_] = *(const short8*)&As[r_ * 64 + ((cg_ ^ (r_ & 7)) << 3)];  \
            }                                                                          \
        }                                                                              \
    }
#define LDB_ALL                                                                        \
    {                                                                                  \
        _Pragma("unroll")                                                              \
        for (int nf_ = 0; nf_ < 4; ++nf_) {                                            \
            _Pragma("unroll")                                                          \
            for (int ks_ = 0; ks_ < 2; ++ks_) {                                        \
                int r_ = wn * 64 + nf_ * 16 + ln;                                      \
                int cg_ = ks_ * 4 + quad;                                              \
                b[nf_][ks_] = *(const short8*)&Bs[r_ * 64 + ((cg_ ^ (r_ & 7)) << 3)];  \
            }                                                                          \
        }                                                                              \
    }
#define MM_H(mh)                                                                       \
    {                                                                                  \
        __builtin_amdgcn_s_setprio(1);                                                 \
        _Pragma("unroll")                                                              \
        for (int mf_ = 0; mf_ < 4; ++mf_)                                              \
            _Pragma("unroll")                                                          \
            for (int nf_ = 0; nf_ < 4; ++nf_)                                          \
                _Pragma("unroll")                                                      \
                for (int ks_ = 0; ks_ < 2; ++ks_)                                      \
                    acc[(mh) * 4 + mf_][nf_] =                                         \
                        __builtin_amdgcn_mfma_f32_16x16x32_bf16(                       \
                            a[mf_][ks_], b[nf_][ks_],                                  \
                            acc[(mh) * 4 + mf_][nf_], 0, 0, 0);                        \
        __builtin_amdgcn_s_setprio(0);                                                 \
    }

    STAGE(0, 0) STAGE(0, 1) STAGE(0, 2) STAGE(0, 3)
    VM0; SB0;
    BAR; SB0;

    #pragma unroll 2
    for (int t = 0; t < 16; ++t) {
        As = lsA + (t & 1) * 16384;
        Bs = lsB + (t & 1) * 16384;
        if (t < 15) { STAGE(t + 1, 0) STAGE(t + 1, 1) STAGE(t + 1, 2) STAGE(t + 1, 3) }
        SB0;
        LDA(0) LDB_ALL
        MM_H(0)
        LDA(1)
        MM_H(1)
        LGKM0; SB0;
        if (t < 15) {
            VM0; SB0;
            BAR; SB0;
        }
    }

#undef STAGE_HALF
#undef STAGE
#undef LDA
#undef LDB_ALL
#undef MM_H

    if (z != 2) {
        unsigned short* __restrict__ Y = (z == 0) ? Q : K;
        #pragma unroll
        for (int mf = 0; mf < 8; ++mf)
            #pragma unroll
            for (int nf = 0; nf < 4; ++nf)
                #pragma unroll
                for (int rr = 0; rr < 4; ++rr) {
                    int row = m0 + wm * 128 + mf * 16 + quad * 4 + rr;
                    int col = n0 + wn * 64 + nf * 16 + ln;
                    Y[(size_t)row * D_ + col] = f2bf(acc[mf][nf][rr] * scale);
                }
    } else {
        // transposed store: Vt[b][e][s].  Per-wave LDS transpose, packed u32.
        BAR;                                   // all waves done with buffer reads
        unsigned int* U = (unsigned int*)ls + w * 2080;     // [32 e][65 u32]
        const int b_ = m0 >> 12;                            // batch
        const int sbase = (m0 & 4095) + wm * 128;           // s within batch
        unsigned int* VtU = (unsigned int*)Vt;
        #pragma unroll
        for (int ch = 0; ch < 2; ++ch) {
            #pragma unroll
            for (int nfl = 0; nfl < 2; ++nfl) {
                int nf = ch * 2 + nfl;
                int el = nfl * 16 + ln;
                #pragma unroll
                for (int mf = 0; mf < 8; ++mf)
                    #pragma unroll
                    for (int pr = 0; pr < 2; ++pr) {
                        unsigned lo = f2bf(acc[mf][nf][2 * pr]);
                        unsigned hi = f2bf(acc[mf][nf][2 * pr + 1]);
                        U[el * 65 + mf * 8 + quad * 2 + pr] = lo | (hi << 16);
                    }
            }
            LGKM0; SB0;     // writes visible to own wave's reads
            #pragma unroll 4
            for (int el = 0; el < 32; ++el) {
                unsigned v = U[el * 65 + lane];
                int eg = n0 + wn * 64 + ch * 32 + el;
                VtU[(((size_t)b_ * D_ + eg) * S_ + sbase) / 2 + lane] = v;
            }
            if (ch == 0) { LGKM0; SB0; }   // reads done before chunk-1 writes
        }
    }
}

// ---------------------------------------------------------------------------
// qk_pexp: P = exp(Q@K^T) bf16 tile-packed + partial row sums.  (unchanged)
// kt-PAIRED blocks 128q x 256k; even-qt diagonal solo path; BK=32 ring-of-3.
// ---------------------------------------------------------------------------
__global__ __launch_bounds__(256, 2) void qk_pexp(
    const unsigned short* __restrict__ Q, const unsigned short* __restrict__ K,
    unsigned short* __restrict__ P, float* __restrict__ lpart)
{
    __shared__ __align__(16) unsigned short ls[3 * 12288];   // 72 KB ring
    __shared__ float sml[2][128];

    const int l = blockIdx.x, b = blockIdx.y;
    const int r = l & 7;          // xcd
    const int s = l >> 3;         // 0..33: 0-31 pairs, 32-33 solo diagonals
    const size_t base = (size_t)b * S_ * D_;
    const int tid = threadIdx.x, lane = tid & 63, w = tid >> 6;
    const int wm = w >> 1, wn = w & 1, quad = lane >> 4, ln = lane & 15;

    if (s < 32) {
        const int qts0 = r, qts1 = 31 - r, qts2 = 8 + r, qts3 = 23 - r;
        int qt = -1, j = 0, rem = s;
        {
            int np;
            np = (qts0 + 1) >> 1; if (rem < np) { qt = qts0; j = rem; } rem -= np;
            np = (qts1 + 1) >> 1; if (qt < 0 && rem < np) { qt = qts1; j = rem; } if (qt < 0) rem -= np;
            np = (qts2 + 1) >> 1; if (qt < 0 && rem < np) { qt = qts2; j = rem; } if (qt < 0) rem -= np;
            if (qt < 0) { qt = qts3; j = rem; }
        }
        const int q0 = qt * 128;
        const int p0 = qt * (qt + 1) / 2 + 2 * j;
        const unsigned short* Qb  = Q + base + (size_t)q0 * D_;
        const unsigned short* Kb2 = K + base + (size_t)(j * 256) * D_;

#define QP_STAGE(c_, r_)                                                          \
    {                                                                             \
        _Pragma("unroll")                                                         \
        for (int i_ = 0; i_ < 2; ++i_) {                                          \
            int g_ = tid + i_ * 256;                                              \
            int row_ = g_ >> 2;                                                   \
            int gs_ = (g_ & 3) ^ ((row_ >> 1) & 3);                               \
            gld_lds16(Qb + (size_t)row_ * D_ + (c_) * 32 + gs_ * 8,               \
                      ls + (r_) * 12288 + g_ * 8);                                \
        }                                                                         \
        _Pragma("unroll")                                                         \
        for (int i_ = 0; i_ < 4; ++i_) {                                          \
            int g_ = tid + i_ * 256;                                              \
            int row_ = g_ >> 2;                                                   \
            int gs_ = (g_ & 3) ^ ((row_ >> 1) & 3);                               \
            gld_lds16(Kb2 + (size_t)row_ * D_ + (c_) * 32 + gs_ * 8,              \
                      ls + (r_) * 12288 + 4096 + g_ * 8);                         \
        }                                                                         \
    }

        f32x4 acc[4][8] = {};

#define QP_BODY(r_)                                                              \
    {                                                                            \
        const unsigned short* As_ = ls + (r_) * 12288;                           \
        const unsigned short* Bs_ = As_ + 4096;                                  \
        short8 a_[4], b_[8];                                                     \
        _Pragma("unroll")                                                        \
        for (int mf_ = 0; mf_ < 4; ++mf_) {                                      \
            int row_ = wm * 64 + mf_ * 16 + ln;                                  \
            int g_ = quad ^ ((row_ >> 1) & 3);                                   \
            a_[mf_] = *(const short8*)&As_[row_ * 32 + g_ * 8];                  \
        }                                                                        \
        _Pragma("unroll")                                                        \
        for (int nf_ = 0; nf_ < 8; ++nf_) {                                      \
            int row_ = wn * 128 + nf_ * 16 + ln;                                 \
            int g_ = quad ^ ((row_ >> 1) & 3);                                   \
            b_[nf_] = *(const short8*)&Bs_[row_ * 32 + g_ * 8];                  \
        }                                                                        \
        __builtin_amdgcn_s_setprio(1);                                          \
        _Pragma("unroll")                                                        \
        for (int mf_ = 0; mf_ < 4; ++mf_)                                        \
            _Pragma("unroll")                                                    \
            for (int nf_ = 0; nf_ < 8; ++nf_)                                    \
                acc[mf_][nf_] = __builtin_amdgcn_mfma_f32_16x16x32_bf16(         \
                    a_[mf_], b_[nf_], acc[mf_][nf_], 0, 0, 0);                   \
        __builtin_amdgcn_s_setprio(0);                                          \
    }

#define QP_STEP(t, r_, rn, wcode)                                                \
    {                                                                            \
        if ((wcode) == 0) QP_STAGE((t) + 2, rn)                                  \
        SB0;                                                                     \
        QP_BODY(r_)                                                              \
        LGKM0; SB0;                                                              \
        if ((wcode) == 0)      { VM6; SB0; BAR; SB0; }                           \
        else if ((wcode) == 1) { VM0; SB0; BAR; SB0; }                           \
    }

        QP_STAGE(0, 0) QP_STAGE(1, 1)
        VM6; SB0;
        BAR; SB0;

        #pragma unroll 1
        for (int tb = 0; tb < 30; tb += 3) {
            QP_STEP(tb,     0, 2, 0)
            QP_STEP(tb + 1, 1, 0, 0)
            QP_STEP(tb + 2, 2, 1, 0)
        }
        QP_STEP(30, 0, 0, 1)
        QP_STEP(31, 1, 0, 2)

#undef QP_STAGE
#undef QP_BODY
#undef QP_STEP

        const bool mt = (2 * j + 1 == qt) && (wn == 1);   // diagonal tile in pair
        unsigned short* Pt = P + ((size_t)b * PAIRS_ + p0 + wn) * (128 * 128);
        #pragma unroll
        for (int mf = 0; mf < 4; ++mf)
            #pragma unroll
            for (int rr = 0; rr < 4; ++rr) {
                int rowq = wm * 64 + mf * 16 + quad * 4 + rr;
                float lsum = 0.0f;
                #pragma unroll
                for (int nf = 0; nf < 8; ++nf) {
                    int ckey = nf * 16 + ln;
                    float sc = acc[mf][nf][rr];
                    float pe = (mt && ckey > rowq) ? 0.0f : __expf(fminf(sc, 60.0f));
                    Pt[rowq * 128 + ckey] = f2bf(pe);
                    lsum += pe;
                }
                #pragma unroll
                for (int off = 1; off < 16; off <<= 1)
                    lsum += __shfl_xor(lsum, off);
                if (ln == 0) sml[wn][rowq] = lsum;
            }
        __syncthreads();
        if (tid < 128) {
            lpart[((size_t)b * PAIRS_ + p0) * 128 + tid]     = sml[0][tid];
            lpart[((size_t)b * PAIRS_ + p0 + 1) * 128 + tid] = sml[1][tid];
        }
    } else {
        const int qt = (r & 1) ? ((s == 32) ? 31 - r : 23 - r)
                               : ((s == 32) ? r : 8 + r);
        const int q0 = qt * 128;
        const int p = qt * (qt + 1) / 2 + qt;
        const unsigned short* Qb = Q + base + (size_t)q0 * D_;
        const unsigned short* Kb = K + base + (size_t)q0 * D_;

#define QS_STAGE(c_, r_)                                                          \
    {                                                                             \
        _Pragma("unroll")                                                         \
        for (int i_ = 0; i_ < 2; ++i_) {                                          \
            int g_ = tid + i_ * 256;                                              \
            int row_ = g_ >> 2;                                                   \
            int gs_ = (g_ & 3) ^ ((row_ >> 1) & 3);                               \
            gld_lds16(Qb + (size_t)row_ * D_ + (c_) * 32 + gs_ * 8,               \
                      ls + (r_) * 12288 + g_ * 8);                                \
            gld_lds16(Kb + (size_t)row_ * D_ + (c_) * 32 + gs_ * 8,               \
                      ls + (r_) * 12288 + 4096 + g_ * 8);                         \
        }                                                                         \
    }

        f32x4 acc[4][4] = {};

#define QS_BODY(r_)                                                              \
    {                                                                            \
        const unsigned short* As_ = ls + (r_) * 12288;                           \
        const unsigned short* Bs_ = As_ + 4096;                                  \
        short8 a_[4], b_[4];                                                     \
        _Pragma("unroll")                                                        \
        for (int mf_ = 0; mf_ < 4; ++mf_) {                                      \
            int row_ = wm * 64 + mf_ * 16 + ln;                                  \
            int g_ = quad ^ ((row_ >> 1) & 3);                                   \
            a_[mf_] = *(const short8*)&As_[row_ * 32 + g_ * 8];                  \
        }                                                                        \
        _Pragma("unroll")                                                        \
        for (int nf_ = 0; nf_ < 4; ++nf_) {                                      \
            int row_ = wn * 64 + nf_ * 16 + ln;                                  \
            int g_ = quad ^ ((row_ >> 1) & 3);                                   \
            b_[nf_] = *(const short8*)&Bs_[row_ * 32 + g_ * 8];                  \
        }                                                                        \
        __builtin_amdgcn_s_setprio(1);                                          \
        _Pragma("unroll")                                                        \
        for (int mf_ = 0; mf_ < 4; ++mf_)                                        \
            _Pragma("unroll")                                                    \
            for (int nf_ = 0; nf_ < 4; ++nf_)                                    \
                acc[mf_][nf_] = __builtin_amdgcn_mfma_f32_16x16x32_bf16(         \
                    a_[mf_], b_[nf_], acc[mf_][nf_], 0, 0, 0);                   \
        __builtin_amdgcn_s_setprio(0);                                          \
    }

#define QS_STEP(t, r_, rn, wcode)                                                \
    {                                                                            \
        if ((wcode) == 0) QS_STAGE((t) + 2, rn)                                  \
        SB0;                                                                     \
        QS_BODY(r_)                                                              \
        LGKM0; SB0;                                                              \
        if ((wcode) == 0)      { VM4; SB0; BAR; SB0; }                           \
        else if ((wcode) == 1) { VM0; SB0; BAR; SB0; }                           \
    }

        QS_STAGE(0, 0) QS_STAGE(1, 1)
        VM4; SB0;
        BAR; SB0;

        #pragma unroll 1
        for (int tb = 0; tb < 30; tb += 3) {
            QS_STEP(tb,     0, 2, 0)
            QS_STEP(tb + 1, 1, 0, 0)
            QS_STEP(tb + 2, 2, 1, 0)
        }
        QS_STEP(30, 0, 0, 1)
        QS_STEP(31, 1, 0, 2)

#undef QS_STAGE
#undef QS_BODY
#undef QS_STEP

        unsigned short* Pt = P + ((size_t)b * PAIRS_ + p) * (128 * 128);
        #pragma unroll
        for (int mf = 0; mf < 4; ++mf)
            #pragma unroll
            for (int rr = 0; rr < 4; ++rr) {
                int rowq = wm * 64 + mf * 16 + quad * 4 + rr;
                float lsum = 0.0f;
                #pragma unroll
                for (int nf = 0; nf < 4; ++nf) {
                    int ckey = wn * 64 + nf * 16 + ln;
                    float sc = acc[mf][nf][rr];
                    float pe = (ckey > rowq) ? 0.0f : __expf(fminf(sc, 60.0f));
                    Pt[rowq * 128 + ckey] = f2bf(pe);
                    lsum += pe;
                }
                #pragma unroll
                for (int off = 1; off < 16; off <<= 1)
                    lsum += __shfl_xor(lsum, off);
                if (ln == 0) sml[wn][rowq] = lsum;
            }
        __syncthreads();
        if (tid < 128)
            lpart[((size_t)b * PAIRS_ + p) * 128 + tid] = sml[0][tid] + sml[1][tid];
    }
}

// ---------------------------------------------------------------------------
// merge_il: il[b][q] = 1 / sum_kt l_t
// ---------------------------------------------------------------------------
__global__ __launch_bounds__(128) void merge_il(const float* __restrict__ lpart,
                                                float* __restrict__ il) {
    const int qt = blockIdx.x, b = blockIdx.y;
    const int row = threadIdx.x;
    const int pbase = qt * (qt + 1) / 2;
    float l = 0.0f;
    for (int kt = 0; kt <= qt; ++kt)
        l += lpart[((size_t)b * PAIRS_ + pbase + kt) * 128 + row];
    il[(size_t)b * S_ + qt * 128 + row] = 1.0f / l;
}

// ---------------------------------------------------------------------------
// pv_gemm: O = (P @ V) * il.  128x128 tiles, paired q-tiles, sibling remap.
// NEW: A (P) loaded GLOBAL->VGPR directly (L2-hit via sibling remap; the MFMA
// fragment is a contiguous 16B at P + row*128 + c*32 + quad*8).  B (Vt) is
// reg-staged (global->reg->ds_write, T14) into a 16 KB ring-of-2 with 2-way
// swizzle on the ds_write/ds_read address.  All waits are compiler-tracked
// register dependencies; one barrier per step.  Halves pv's LDS traffic.
// ---------------------------------------------------------------------------
__global__ __launch_bounds__(256, 3) void pv_gemm(
    const unsigned short* __restrict__ P, const unsigned short* __restrict__ Vt,
    const float* __restrict__ il, float* __restrict__ O)
{
    __shared__ __align__(16) unsigned short lsB[2 * 4096];   // 16 KB, B ring-of-2

    const int bid = blockIdx.x;                      // 0..511
    const int u  = (bid & 7) | ((bid >> 6) << 3);    // 0..63  (b*16+pair)
    const int dt = (bid >> 3) & 7;                   // 0..7   d-slice
    const int pair = u & 15;
    const int b = u >> 4;
    const int d0 = dt * 128;
    const int tid = threadIdx.x, lane = tid & 63, w = tid >> 6;
    const int wm = w >> 1, wn = w & 1, quad = lane >> 4, ln = lane & 15;

    const unsigned short* Vtb = Vt + ((size_t)b * D_ + d0) * S_;

    // B global->reg: step c covers 128 d-rows x 32 s-cols; 2x16B per thread
#define PV_LOADB(c_, arr)                                                         \
    {                                                                             \
        _Pragma("unroll")                                                         \
        for (int i_ = 0; i_ < 2; ++i_) {                                          \
            int g_ = tid + i_ * 256;                                              \
            int row_ = g_ >> 2;                                                   \
            arr[i_] = *(const short8*)&Vtb[(size_t)row_ * S_ + (c_) * 32 +        \
                                           (g_ & 3) * 8];                         \
        }                                                                         \
    }
    // B reg->LDS with 2-way swizzle (granule ^= (row>>1)&3)
#define PV_WRITEB(arr, sl_)                                                       \
    {                                                                             \
        _Pragma("unroll")                                                         \
        for (int i_ = 0; i_ < 2; ++i_) {                                          \
            int g_ = tid + i_ * 256;                                              \
            int row_ = g_ >> 2;                                                   \
            int sw_ = (g_ & 3) ^ ((row_ >> 1) & 3);                               \
            *(short8*)&lsB[(sl_) * 4096 + row_ * 32 + sw_ * 8] = arr[i_];         \
        }                                                                         \
    }
    // A global->reg: the MFMA A-fragment for step t (16B contiguous)
#define PV_LOADA(t_, arr)                                                         \
    {                                                                             \
        const unsigned short* Pt_ = Pbase + (size_t)((t_) >> 2) * (128 * 128) +   \
                                    ((t_) & 3) * 32;                              \
        _Pragma("unroll")                                                         \
        for (int mf_ = 0; mf_ < 4; ++mf_)                                         \
            arr[mf_] = *(const short8*)&Pt_[(wm * 64 + mf_ * 16 + ln) * 128 +     \
                                            quad * 8];                            \
    }
#define PV_BODY(sl_, arr)                                                         \
    {                                                                             \
        short8 bf_[4];                                                            \
        _Pragma("unroll")                                                         \
        for (int nf_ = 0; nf_ < 4; ++nf_) {                                       \
            int row_ = wn * 64 + nf_ * 16 + ln;                                   \
            int g_ = quad ^ ((row_ >> 1) & 3);                                    \
            bf_[nf_] = *(const short8*)&lsB[(sl_) * 4096 + row_ * 32 + g_ * 8];   \
        }                                                                         \
        __builtin_amdgcn_s_setprio(1);                                           \
        _Pragma("unroll")                                                         \
        for (int mf_ = 0; mf_ < 4; ++mf_)                                         \
            _Pragma("unroll")                                                     \
            for (int nf_ = 0; nf_ < 4; ++nf_)                                     \
                acc[mf_][nf_] = __builtin_amdgcn_mfma_f32_16x16x32_bf16(          \
                    arr[mf_], bf_[nf_], acc[mf_][nf_], 0, 0, 0);                  \
        __builtin_amdgcn_s_setprio(0);                                           \
    }
    // one step: prefetch B(t+2)/A(t+1), compute t, write B(t+1), barrier
#define PV_ITER(t_, acur, anxt, brfree, brwr, sl_)                                \
    {                                                                             \
        if ((t_) + 2 < nst) PV_LOADB((t_) + 2, brfree)                            \
        if ((t_) + 1 < nst) PV_LOADA((t_) + 1, anxt)                              \
        SB0;                                                                      \
        PV_BODY(sl_, acur)                                                        \
        if ((t_) + 1 < nst) { PV_WRITEB(brwr, (sl_) ^ 1) LGKM0; BAR; SB0; }       \
    }

    short8 a0[4], a1[4], br0[2], br1[2];

    #pragma unroll 1
    for (int half = 0; half < 2; ++half) {
        const int qt = half ? pair : (31 - pair);   // heavy first
        const int q0 = qt * 128;
        const int pbase = qt * (qt + 1) / 2;
        const int nst = 4 * (qt + 1);               // always a multiple of 4
        const unsigned short* Pbase = P + ((size_t)b * PAIRS_ + pbase) * (128 * 128);

        f32x4 acc[4][4] = {};

        // prologue
        PV_LOADB(0, br0)
        PV_LOADB(1, br1)
        PV_LOADA(0, a0)
        if (half) { BAR; }          // protect ring slot reuse across halves
        PV_WRITEB(br0, 0)
        LGKM0; BAR; SB0;

        #pragma unroll 1
        for (int t = 0; t < nst; t += 2) {
            PV_ITER(t,     a0, a1, br0, br1, 0)
            PV_ITER(t + 1, a1, a0, br1, br0, 1)
        }

        #pragma unroll
        for (int mf = 0; mf < 4; ++mf) {
            float ilv[4];
            #pragma unroll
            for (int rr = 0; rr < 4; ++rr)
                ilv[rr] = il[(size_t)b * S_ + q0 + wm * 64 + mf * 16 + quad * 4 + rr];
            #pragma unroll
            for (int nf = 0; nf < 4; ++nf)
                #pragma unroll
                for (int rr = 0; rr < 4; ++rr) {
                    int rowq = q0 + wm * 64 + mf * 16 + quad * 4 + rr;
                    int col = d0 + wn * 64 + nf * 16 + ln;
                    O[((size_t)b * S_ + rowq) * D_ + col] = acc[mf][nf][rr] * ilv[rr];
                }
        }
    }
#undef PV_LOADB
#undef PV_WRITEB
#undef PV_LOADA
#undef PV_BODY
#undef PV_ITER
}

extern "C" void kernel_launch(void* const* d_in, const int* in_sizes, int n_in,
                              void* d_out, int out_size, void* d_ws, size_t ws_size,
                              hipStream_t stream) {
    const float* x  = (const float*)d_in[0];
    const float* Wq = (const float*)d_in[1];
    const float* Wk = (const float*)d_in[2];
    const float* Wv = (const float*)d_in[3];

    const size_t nQ = (size_t)B_ * S_ * D_;
    const size_t nP = (size_t)B_ * PAIRS_ * 128 * 128;

    unsigned short* P  = (unsigned short*)d_ws;
    unsigned short* xb = P;                       // alias: dead before P written
    unsigned short* Q  = P + nP;
    unsigned short* K  = Q + nQ;
    unsigned short* Vt = K + nQ;
    unsigned short* Wt = Vt + nQ;
    float* lpart = (float*)(Wt + (size_t)3 * D_ * D_);
    float* il    = lpart + (size_t)B_ * PAIRS_ * 128;
    float* O = (float*)d_out;

    hipLaunchKernelGGL(prep_x, dim3(8192), dim3(256), 0, stream, x, xb);
    hipLaunchKernelGGL(prep_w, dim3(16, 16, 3), dim3(256), 0, stream, Wq, Wk, Wv, Wt);
    hipLaunchKernelGGL(qkv_gemm, dim3(256, 1, 3), dim3(512), 0, stream, xb, Wt, Q, K, Vt);
    hipLaunchKernelGGL(qk_pexp, dim3(272, B_), dim3(256), 0, stream, Q, K, P, lpart);
    hipLaunchKernelGGL(merge_il, dim3(NT_, B_), dim3(128), 0, stream, lpart, il);
    hipLaunchKernelGGL(pv_gemm, dim3(512), dim3(256), 0, stream, P, Vt, il, O);
}

// Round 8
// 402.778 us; speedup vs baseline: 1.2278x; 1.2278x over previous
//
#include <hip/hip_runtime.h>
#include <hip/hip_bf16.h>

#define B_ 4
#define S_ 4096
#define D_ 1024
#define NT_ 32        // S_/128
#define PAIRS_ 528    // NT_*(NT_+1)/2 lower-triangle tile pairs

typedef __attribute__((ext_vector_type(8))) short short8;
typedef __attribute__((ext_vector_type(4))) float f32x4;

__device__ __forceinline__ unsigned short f2bf(float f) {
    union { float f; unsigned u; } v; v.f = f;
    unsigned u = v.u;
    return (unsigned short)((u + 0x7fffu + ((u >> 16) & 1u)) >> 16);
}

// async global->LDS, 16B per lane. LDS dst is wave-uniform base + lane*16.
__device__ __forceinline__ void gld_lds16(const unsigned short* g, unsigned short* l) {
    __builtin_amdgcn_global_load_lds((const __attribute__((address_space(1))) void*)g,
                                     (__attribute__((address_space(3))) void*)l, 16, 0, 0);
}

#define LGKM0 asm volatile("s_waitcnt lgkmcnt(0)" ::: "memory")
#define VM0   asm volatile("s_waitcnt vmcnt(0)" ::: "memory")
#define VM4   asm volatile("s_waitcnt vmcnt(4)" ::: "memory")
#define VM6   asm volatile("s_waitcnt vmcnt(6)" ::: "memory")
#define BAR   __builtin_amdgcn_s_barrier()
#define SB0   __builtin_amdgcn_sched_barrier(0)

// ---------------------------------------------------------------------------
// prep_x: fp32 x -> bf16 xb
// ---------------------------------------------------------------------------
__global__ __launch_bounds__(256) void prep_x(const float* __restrict__ x,
                                              unsigned short* __restrict__ xb) {
    size_t i = ((size_t)blockIdx.x * 256 + threadIdx.x) * 8;
    float4 a = *(const float4*)&x[i];
    float4 b = *(const float4*)&x[i + 4];
    unsigned u0 = (unsigned)f2bf(a.x) | ((unsigned)f2bf(a.y) << 16);
    unsigned u1 = (unsigned)f2bf(a.z) | ((unsigned)f2bf(a.w) << 16);
    unsigned u2 = (unsigned)f2bf(b.x) | ((unsigned)f2bf(b.y) << 16);
    unsigned u3 = (unsigned)f2bf(b.z) | ((unsigned)f2bf(b.w) << 16);
    uint4 val; val.x = u0; val.y = u1; val.z = u2; val.w = u3;
    *(uint4*)&xb[i] = val;
}

// ---------------------------------------------------------------------------
// prep_w: W[k][n] fp32 -> Wt[n][k] bf16
// ---------------------------------------------------------------------------
__global__ __launch_bounds__(256) void prep_w(const float* __restrict__ Wq,
                                              const float* __restrict__ Wk,
                                              const float* __restrict__ Wv,
                                              unsigned short* __restrict__ Wt) {
    __shared__ float ls[64 * 65];
    const int z = blockIdx.z;
    const float* __restrict__ W = (z == 0) ? Wq : (z == 1) ? Wk : Wv;
    unsigned short* __restrict__ Wtz = Wt + (size_t)z * D_ * D_;
    const int k0 = blockIdx.y * 64, n0 = blockIdx.x * 64;
    const int tid = threadIdx.x;
    #pragma unroll
    for (int i = 0; i < 16; ++i) {
        int lin = i * 256 + tid, r = lin >> 6, c = lin & 63;
        ls[r * 65 + c] = W[(size_t)(k0 + r) * D_ + n0 + c];
    }
    __syncthreads();
    #pragma unroll
    for (int i = 0; i < 16; ++i) {
        int lin = i * 256 + tid, r = lin >> 6, c = lin & 63;
        Wtz[(size_t)(n0 + r) * D_ + k0 + c] = f2bf(ls[c * 65 + r]);
    }
}

// ---------------------------------------------------------------------------
// qkv_gemm: Y = xb @ Wt_z^T.  Round-4 structure (best in-run 108.4us):
// 256x256 tile, BK=64, 2 LDS buffers (128 KB), 8 waves (2x4), source-swizzled
// staging + swizzled ds_read, single barrier per K-tile, free-run body,
// B fragments resident. z==2 writes Vt directly via LDS-transpose epilogue.
// ---------------------------------------------------------------------------
__global__ __launch_bounds__(512, 2) void qkv_gemm(
    const unsigned short* __restrict__ xb, const unsigned short* __restrict__ Wt,
    unsigned short* __restrict__ Q, unsigned short* __restrict__ K,
    unsigned short* __restrict__ Vt)
{
    __shared__ __align__(16) unsigned short ls[65536];   // 128 KiB
    unsigned short* const lsA = ls;            // 2 x 16384
    unsigned short* const lsB = ls + 32768;    // 2 x 16384

    const int z = blockIdx.z;
    const float scale = (z == 0) ? 0.03125f : 1.0f;

    const int lin = blockIdx.x;                       // 0..255
    const int wg = (lin & 7) * 32 + (lin >> 3);       // XCD-contiguous
    const int m0 = (wg >> 2) * 256, n0 = (wg & 3) * 256;

    const int tid = threadIdx.x, lane = tid & 63, w = tid >> 6;
    const int wm = w >> 2, wn = w & 3;                // 2 x 4 wave grid
    const int quad = lane >> 4, ln = lane & 15;

    const unsigned short* Ab = xb + (size_t)m0 * D_;
    const unsigned short* Bb = Wt + (size_t)z * D_ * D_ + (size_t)n0 * D_;

#define STAGE_HALF(gbase, ldsbase)                                              \
    {                                                                           \
        _Pragma("unroll")                                                       \
        for (int i_ = 0; i_ < 2; ++i_) {                                        \
            int g_ = tid + i_ * 512;                                            \
            int r_ = g_ >> 3;                                                   \
            int cg_ = (g_ & 7) ^ (r_ & 7);                                      \
            gld_lds16((gbase) + (size_t)r_ * D_ + cg_ * 8, (ldsbase) + g_ * 8); \
        }                                                                       \
    }
#define STAGE(kt, h)                                                                   \
    {                                                                                  \
        if ((h) < 2) { STAGE_HALF(Ab + (size_t)((h) * 128) * D_ + (kt) * 64,           \
                                  &lsA[(((kt) & 1) * 2 + (h)) * 8192]) }               \
        else         { STAGE_HALF(Bb + (size_t)(((h) - 2) * 128) * D_ + (kt) * 64,     \
                                  &lsB[(((kt) & 1) * 2 + ((h) - 2)) * 8192]) }         \
    }

    const unsigned short* As;
    const unsigned short* Bs;
    short8 a[4][2], b[4][2];
    f32x4 acc[8][4] = {};

#define LDA(mh)                                                                        \
    {                                                                                  \
        _Pragma("unroll")                                                              \
        for (int mf_ = 0; mf_ < 4; ++mf_) {                                            \
            _Pragma("unroll")                                                          \
            for (int ks_ = 0; ks_ < 2; ++ks_) {                                        \
                int r_ = wm * 128 + ((mh) * 4 + mf_) * 16 + ln;                        \
                int cg_ = ks_ * 4 + quad;                                              \
                a[mf_][ks_] = *(const short8*)&As[r_ * 64 + ((cg_ ^ (r_ & 7)) << 3)];  \
            }                                                                          \
        }                                                                              \
    }
#define LDB_ALL                                                                        \
    {                                                                                  \
        _Pragma("unroll")                                                              \
        for (int nf_ = 0; nf_ < 4; ++nf_) {                                            \
            _Pragma("unroll")                                                          \
            for (int ks_ = 0; ks_ < 2; ++ks_) {                                        \
                int r_ = wn * 64 + nf_ * 16 + ln;                                      \
                int cg_ = ks_ * 4 + quad;                                              \
                b[nf_][ks_] = *(const short8*)&Bs[r_ * 64 + ((cg_ ^ (r_ & 7)) << 3)];  \
            }                                                                          \
        }                                                                              \
    }
#define MM_H(mh)                                                                       \
    {                                                                                  \
        __builtin_amdgcn_s_setprio(1);                                                 \
        _Pragma("unroll")                                                              \
        for (int mf_ = 0; mf_ < 4; ++mf_)                                              \
            _Pragma("unroll")                                                          \
            for (int nf_ = 0; nf_ < 4; ++nf_)                                          \
                _Pragma("unroll")                                                      \
                for (int ks_ = 0; ks_ < 2; ++ks_)                                      \
                    acc[(mh) * 4 + mf_][nf_] =                                         \
                        __builtin_amdgcn_mfma_f32_16x16x32_bf16(                       \
                            a[mf_][ks_], b[nf_][ks_],                                  \
                            acc[(mh) * 4 + mf_][nf_], 0, 0, 0);                        \
        __builtin_amdgcn_s_setprio(0);                                                 \
    }

    STAGE(0, 0) STAGE(0, 1) STAGE(0, 2) STAGE(0, 3)
    VM0; SB0;
    BAR; SB0;

    #pragma unroll 2
    for (int t = 0; t < 16; ++t) {
        As = lsA + (t & 1) * 16384;
        Bs = lsB + (t & 1) * 16384;
        if (t < 15) { STAGE(t + 1, 0) STAGE(t + 1, 1) STAGE(t + 1, 2) STAGE(t + 1, 3) }
        SB0;
        LDA(0) LDB_ALL
        MM_H(0)
        LDA(1)
        MM_H(1)
        LGKM0; SB0;
        if (t < 15) {
            VM0; SB0;
            BAR; SB0;
        }
    }

#undef STAGE_HALF
#undef STAGE
#undef LDA
#undef LDB_ALL
#undef MM_H

    if (z != 2) {
        unsigned short* __restrict__ Y = (z == 0) ? Q : K;
        #pragma unroll
        for (int mf = 0; mf < 8; ++mf)
            #pragma unroll
            for (int nf = 0; nf < 4; ++nf)
                #pragma unroll
                for (int rr = 0; rr < 4; ++rr) {
                    int row = m0 + wm * 128 + mf * 16 + quad * 4 + rr;
                    int col = n0 + wn * 64 + nf * 16 + ln;
                    Y[(size_t)row * D_ + col] = f2bf(acc[mf][nf][rr] * scale);
                }
    } else {
        // transposed store: Vt[b][e][s].  Per-wave LDS transpose, packed u32.
        BAR;                                   // all waves done with buffer reads
        unsigned int* U = (unsigned int*)ls + w * 2080;     // [32 e][65 u32]
        const int b_ = m0 >> 12;                            // batch
        const int sbase = (m0 & 4095) + wm * 128;           // s within batch
        unsigned int* VtU = (unsigned int*)Vt;
        #pragma unroll
        for (int ch = 0; ch < 2; ++ch) {
            #pragma unroll
            for (int nfl = 0; nfl < 2; ++nfl) {
                int nf = ch * 2 + nfl;
                int el = nfl * 16 + ln;
                #pragma unroll
                for (int mf = 0; mf < 8; ++mf)
                    #pragma unroll
                    for (int pr = 0; pr < 2; ++pr) {
                        unsigned lo = f2bf(acc[mf][nf][2 * pr]);
                        unsigned hi = f2bf(acc[mf][nf][2 * pr + 1]);
                        U[el * 65 + mf * 8 + quad * 2 + pr] = lo | (hi << 16);
                    }
            }
            LGKM0; SB0;     // writes visible to own wave's reads
            #pragma unroll 4
            for (int el = 0; el < 32; ++el) {
                unsigned v = U[el * 65 + lane];
                int eg = n0 + wn * 64 + ch * 32 + el;
                VtU[(((size_t)b_ * D_ + eg) * S_ + sbase) / 2 + lane] = v;
            }
            if (ch == 0) { LGKM0; SB0; }   // reads done before chunk-1 writes
        }
    }
}

// ---------------------------------------------------------------------------
// qk_pexp: P = exp(Q@K^T) bf16 tile-packed + partial row sums.  (unchanged)
// kt-PAIRED blocks 128q x 256k; even-qt diagonal solo path; BK=32 ring-of-3.
// ---------------------------------------------------------------------------
__global__ __launch_bounds__(256, 2) void qk_pexp(
    const unsigned short* __restrict__ Q, const unsigned short* __restrict__ K,
    unsigned short* __restrict__ P, float* __restrict__ lpart)
{
    __shared__ __align__(16) unsigned short ls[3 * 12288];   // 72 KB ring
    __shared__ float sml[2][128];

    const int l = blockIdx.x, b = blockIdx.y;
    const int r = l & 7;          // xcd
    const int s = l >> 3;         // 0..33: 0-31 pairs, 32-33 solo diagonals
    const size_t base = (size_t)b * S_ * D_;
    const int tid = threadIdx.x, lane = tid & 63, w = tid >> 6;
    const int wm = w >> 1, wn = w & 1, quad = lane >> 4, ln = lane & 15;

    if (s < 32) {
        const int qts0 = r, qts1 = 31 - r, qts2 = 8 + r, qts3 = 23 - r;
        int qt = -1, j = 0, rem = s;
        {
            int np;
            np = (qts0 + 1) >> 1; if (rem < np) { qt = qts0; j = rem; } rem -= np;
            np = (qts1 + 1) >> 1; if (qt < 0 && rem < np) { qt = qts1; j = rem; } if (qt < 0) rem -= np;
            np = (qts2 + 1) >> 1; if (qt < 0 && rem < np) { qt = qts2; j = rem; } if (qt < 0) rem -= np;
            if (qt < 0) { qt = qts3; j = rem; }
        }
        const int q0 = qt * 128;
        const int p0 = qt * (qt + 1) / 2 + 2 * j;
        const unsigned short* Qb  = Q + base + (size_t)q0 * D_;
        const unsigned short* Kb2 = K + base + (size_t)(j * 256) * D_;

#define QP_STAGE(c_, r_)                                                          \
    {                                                                             \
        _Pragma("unroll")                                                         \
        for (int i_ = 0; i_ < 2; ++i_) {                                          \
            int g_ = tid + i_ * 256;                                              \
            int row_ = g_ >> 2;                                                   \
            int gs_ = (g_ & 3) ^ ((row_ >> 1) & 3);                               \
            gld_lds16(Qb + (size_t)row_ * D_ + (c_) * 32 + gs_ * 8,               \
                      ls + (r_) * 12288 + g_ * 8);                                \
        }                                                                         \
        _Pragma("unroll")                                                         \
        for (int i_ = 0; i_ < 4; ++i_) {                                          \
            int g_ = tid + i_ * 256;                                              \
            int row_ = g_ >> 2;                                                   \
            int gs_ = (g_ & 3) ^ ((row_ >> 1) & 3);                               \
            gld_lds16(Kb2 + (size_t)row_ * D_ + (c_) * 32 + gs_ * 8,              \
                      ls + (r_) * 12288 + 4096 + g_ * 8);                         \
        }                                                                         \
    }

        f32x4 acc[4][8] = {};

#define QP_BODY(r_)                                                              \
    {                                                                            \
        const unsigned short* As_ = ls + (r_) * 12288;                           \
        const unsigned short* Bs_ = As_ + 4096;                                  \
        short8 a_[4], b_[8];                                                     \
        _Pragma("unroll")                                                        \
        for (int mf_ = 0; mf_ < 4; ++mf_) {                                      \
            int row_ = wm * 64 + mf_ * 16 + ln;                                  \
            int g_ = quad ^ ((row_ >> 1) & 3);                                   \
            a_[mf_] = *(const short8*)&As_[row_ * 32 + g_ * 8];                  \
        }                                                                        \
        _Pragma("unroll")                                                        \
        for (int nf_ = 0; nf_ < 8; ++nf_) {                                      \
            int row_ = wn * 128 + nf_ * 16 + ln;                                 \
            int g_ = quad ^ ((row_ >> 1) & 3);                                   \
            b_[nf_] = *(const short8*)&Bs_[row_ * 32 + g_ * 8];                  \
        }                                                                        \
        __builtin_amdgcn_s_setprio(1);                                          \
        _Pragma("unroll")                                                        \
        for (int mf_ = 0; mf_ < 4; ++mf_)                                        \
            _Pragma("unroll")                                                    \
            for (int nf_ = 0; nf_ < 8; ++nf_)                                    \
                acc[mf_][nf_] = __builtin_amdgcn_mfma_f32_16x16x32_bf16(         \
                    a_[mf_], b_[nf_], acc[mf_][nf_], 0, 0, 0);                   \
        __builtin_amdgcn_s_setprio(0);                                          \
    }

#define QP_STEP(t, r_, rn, wcode)                                                \
    {                                                                            \
        if ((wcode) == 0) QP_STAGE((t) + 2, rn)                                  \
        SB0;                                                                     \
        QP_BODY(r_)                                                              \
        LGKM0; SB0;                                                              \
        if ((wcode) == 0)      { VM6; SB0; BAR; SB0; }                           \
        else if ((wcode) == 1) { VM0; SB0; BAR; SB0; }                           \
    }

        QP_STAGE(0, 0) QP_STAGE(1, 1)
        VM6; SB0;
        BAR; SB0;

        #pragma unroll 1
        for (int tb = 0; tb < 30; tb += 3) {
            QP_STEP(tb,     0, 2, 0)
            QP_STEP(tb + 1, 1, 0, 0)
            QP_STEP(tb + 2, 2, 1, 0)
        }
        QP_STEP(30, 0, 0, 1)
        QP_STEP(31, 1, 0, 2)

#undef QP_STAGE
#undef QP_BODY
#undef QP_STEP

        const bool mt = (2 * j + 1 == qt) && (wn == 1);   // diagonal tile in pair
        unsigned short* Pt = P + ((size_t)b * PAIRS_ + p0 + wn) * (128 * 128);
        #pragma unroll
        for (int mf = 0; mf < 4; ++mf)
            #pragma unroll
            for (int rr = 0; rr < 4; ++rr) {
                int rowq = wm * 64 + mf * 16 + quad * 4 + rr;
                float lsum = 0.0f;
                #pragma unroll
                for (int nf = 0; nf < 8; ++nf) {
                    int ckey = nf * 16 + ln;
                    float sc = acc[mf][nf][rr];
                    float pe = (mt && ckey > rowq) ? 0.0f : __expf(fminf(sc, 60.0f));
                    Pt[rowq * 128 + ckey] = f2bf(pe);
                    lsum += pe;
                }
                #pragma unroll
                for (int off = 1; off < 16; off <<= 1)
                    lsum += __shfl_xor(lsum, off);
                if (ln == 0) sml[wn][rowq] = lsum;
            }
        __syncthreads();
        if (tid < 128) {
            lpart[((size_t)b * PAIRS_ + p0) * 128 + tid]     = sml[0][tid];
            lpart[((size_t)b * PAIRS_ + p0 + 1) * 128 + tid] = sml[1][tid];
        }
    } else {
        const int qt = (r & 1) ? ((s == 32) ? 31 - r : 23 - r)
                               : ((s == 32) ? r : 8 + r);
        const int q0 = qt * 128;
        const int p = qt * (qt + 1) / 2 + qt;
        const unsigned short* Qb = Q + base + (size_t)q0 * D_;
        const unsigned short* Kb = K + base + (size_t)q0 * D_;

#define QS_STAGE(c_, r_)                                                          \
    {                                                                             \
        _Pragma("unroll")                                                         \
        for (int i_ = 0; i_ < 2; ++i_) {                                          \
            int g_ = tid + i_ * 256;                                              \
            int row_ = g_ >> 2;                                                   \
            int gs_ = (g_ & 3) ^ ((row_ >> 1) & 3);                               \
            gld_lds16(Qb + (size_t)row_ * D_ + (c_) * 32 + gs_ * 8,               \
                      ls + (r_) * 12288 + g_ * 8);                                \
            gld_lds16(Kb + (size_t)row_ * D_ + (c_) * 32 + gs_ * 8,               \
                      ls + (r_) * 12288 + 4096 + g_ * 8);                         \
        }                                                                         \
    }

        f32x4 acc[4][4] = {};

#define QS_BODY(r_)                                                              \
    {                                                                            \
        const unsigned short* As_ = ls + (r_) * 12288;                           \
        const unsigned short* Bs_ = As_ + 4096;                                  \
        short8 a_[4], b_[4];                                                     \
        _Pragma("unroll")                                                        \
        for (int mf_ = 0; mf_ < 4; ++mf_) {                                      \
            int row_ = wm * 64 + mf_ * 16 + ln;                                  \
            int g_ = quad ^ ((row_ >> 1) & 3);                                   \
            a_[mf_] = *(const short8*)&As_[row_ * 32 + g_ * 8];                  \
        }                                                                        \
        _Pragma("unroll")                                                        \
        for (int nf_ = 0; nf_ < 4; ++nf_) {                                      \
            int row_ = wn * 64 + nf_ * 16 + ln;                                  \
            int g_ = quad ^ ((row_ >> 1) & 3);                                   \
            b_[nf_] = *(const short8*)&Bs_[row_ * 32 + g_ * 8];                  \
        }                                                                        \
        __builtin_amdgcn_s_setprio(1);                                          \
        _Pragma("unroll")                                                        \
        for (int mf_ = 0; mf_ < 4; ++mf_)                                        \
            _Pragma("unroll")                                                    \
            for (int nf_ = 0; nf_ < 4; ++nf_)                                    \
                acc[mf_][nf_] = __builtin_amdgcn_mfma_f32_16x16x32_bf16(         \
                    a_[mf_], b_[nf_], acc[mf_][nf_], 0, 0, 0);                   \
        __builtin_amdgcn_s_setprio(0);                                          \
    }

#define QS_STEP(t, r_, rn, wcode)                                                \
    {                                                                            \
        if ((wcode) == 0) QS_STAGE((t) + 2, rn)                                  \
        SB0;                                                                     \
        QS_BODY(r_)                                                              \
        LGKM0; SB0;                                                              \
        if ((wcode) == 0)      { VM4; SB0; BAR; SB0; }                           \
        else if ((wcode) == 1) { VM0; SB0; BAR; SB0; }                           \
    }

        QS_STAGE(0, 0) QS_STAGE(1, 1)
        VM4; SB0;
        BAR; SB0;

        #pragma unroll 1
        for (int tb = 0; tb < 30; tb += 3) {
            QS_STEP(tb,     0, 2, 0)
            QS_STEP(tb + 1, 1, 0, 0)
            QS_STEP(tb + 2, 2, 1, 0)
        }
        QS_STEP(30, 0, 0, 1)
        QS_STEP(31, 1, 0, 2)

#undef QS_STAGE
#undef QS_BODY
#undef QS_STEP

        unsigned short* Pt = P + ((size_t)b * PAIRS_ + p) * (128 * 128);
        #pragma unroll
        for (int mf = 0; mf < 4; ++mf)
            #pragma unroll
            for (int rr = 0; rr < 4; ++rr) {
                int rowq = wm * 64 + mf * 16 + quad * 4 + rr;
                float lsum = 0.0f;
                #pragma unroll
                for (int nf = 0; nf < 4; ++nf) {
                    int ckey = wn * 64 + nf * 16 + ln;
                    float sc = acc[mf][nf][rr];
                    float pe = (ckey > rowq) ? 0.0f : __expf(fminf(sc, 60.0f));
                    Pt[rowq * 128 + ckey] = f2bf(pe);
                    lsum += pe;
                }
                #pragma unroll
                for (int off = 1; off < 16; off <<= 1)
                    lsum += __shfl_xor(lsum, off);
                if (ln == 0) sml[wn][rowq] = lsum;
            }
        __syncthreads();
        if (tid < 128)
            lpart[((size_t)b * PAIRS_ + p) * 128 + tid] = sml[0][tid] + sml[1][tid];
    }
}

// ---------------------------------------------------------------------------
// merge_il: il[b][q] = 1 / sum_kt l_t
// ---------------------------------------------------------------------------
__global__ __launch_bounds__(128) void merge_il(const float* __restrict__ lpart,
                                                float* __restrict__ il) {
    const int qt = blockIdx.x, b = blockIdx.y;
    const int row = threadIdx.x;
    const int pbase = qt * (qt + 1) / 2;
    float l = 0.0f;
    for (int kt = 0; kt <= qt; ++kt)
        l += lpart[((size_t)b * PAIRS_ + pbase + kt) * 128 + row];
    il[(size_t)b * S_ + qt * 128 + row] = 1.0f / l;
}

// ---------------------------------------------------------------------------
// pv_gemm: O = (P @ V) * il.  REVERTED to round-5 version (best measured):
// 128x128 tiles, paired q-tiles, BK=32 ring-of-3 (48 KB -> 3 blocks/CU),
// counted vmcnt(4). XCD-sibling remap (all 8 d-slices of a (b,pair) on one
// XCD -> P fetched into that XCD's L2 once, shared 8 ways).
// ---------------------------------------------------------------------------
__global__ __launch_bounds__(256, 3) void pv_gemm(
    const unsigned short* __restrict__ P, const unsigned short* __restrict__ Vt,
    const float* __restrict__ il, float* __restrict__ O)
{
    __shared__ __align__(16) unsigned short ls[3 * 8192];   // 48 KB ring

    const int bid = blockIdx.x;                      // 0..511
    const int u  = (bid & 7) | ((bid >> 6) << 3);    // 0..63  (b*16+pair)
    const int dt = (bid >> 3) & 7;                   // 0..7   d-slice
    const int pair = u & 15;
    const int b = u >> 4;
    const int d0 = dt * 128;
    const int tid = threadIdx.x, lane = tid & 63, w = tid >> 6;
    const int wm = w >> 1, wn = w & 1, quad = lane >> 4, ln = lane & 15;

    const unsigned short* Vtb = Vt + ((size_t)b * D_ + d0) * S_;

#define PV_STAGE(c_, r_)                                                          \
    {                                                                             \
        const unsigned short* Pt_ = Pbase + (size_t)((c_) >> 2) * (128 * 128);    \
        _Pragma("unroll")                                                         \
        for (int i_ = 0; i_ < 2; ++i_) {                                          \
            int g_ = tid + i_ * 256;                                              \
            int row_ = g_ >> 2;                                                   \
            int gs_ = (g_ & 3) ^ ((row_ >> 1) & 3);                               \
            gld_lds16(Pt_ + (size_t)row_ * 128 + ((c_) & 3) * 32 + gs_ * 8,       \
                      ls + (r_) * 8192 + g_ * 8);                                 \
            gld_lds16(Vtb + (size_t)row_ * S_ + (c_) * 32 + gs_ * 8,              \
                      ls + (r_) * 8192 + 4096 + g_ * 8);                          \
        }                                                                         \
    }

#define PV_BODY(r_)                                                              \
    {                                                                            \
        const unsigned short* As_ = ls + (r_) * 8192;                            \
        const unsigned short* Bs_ = As_ + 4096;                                  \
        short8 a_[4], b_[4];                                                     \
        _Pragma("unroll")                                                        \
        for (int mf_ = 0; mf_ < 4; ++mf_) {                                      \
            int row_ = wm * 64 + mf_ * 16 + ln;                                  \
            int g_ = quad ^ ((row_ >> 1) & 3);                                   \
            a_[mf_] = *(const short8*)&As_[row_ * 32 + g_ * 8];                  \
        }                                                                        \
        _Pragma("unroll")                                                        \
        for (int nf_ = 0; nf_ < 4; ++nf_) {                                      \
            int row_ = wn * 64 + nf_ * 16 + ln;                                  \
            int g_ = quad ^ ((row_ >> 1) & 3);                                   \
            b_[nf_] = *(const short8*)&Bs_[row_ * 32 + g_ * 8];                  \
        }                                                                        \
        __builtin_amdgcn_s_setprio(1);                                          \
        _Pragma("unroll")                                                        \
        for (int mf_ = 0; mf_ < 4; ++mf_)                                        \
            _Pragma("unroll")                                                    \
            for (int nf_ = 0; nf_ < 4; ++nf_)                                    \
                acc[mf_][nf_] = __builtin_amdgcn_mfma_f32_16x16x32_bf16(         \
                    a_[mf_], b_[nf_], acc[mf_][nf_], 0, 0, 0);                   \
        __builtin_amdgcn_s_setprio(0);                                          \
    }

    #pragma unroll 1
    for (int half = 0; half < 2; ++half) {
        const int qt = half ? pair : (31 - pair);   // heavy first
        const int q0 = qt * 128;
        const int pbase = qt * (qt + 1) / 2;
        const int nst = 4 * (qt + 1);
        const unsigned short* Pbase = P + ((size_t)b * PAIRS_ + pbase) * (128 * 128);

        f32x4 acc[4][4] = {};

        if (half) { BAR; SB0; }      // protect ring reuse across halves
        PV_STAGE(0, 0) PV_STAGE(1, 1)
        VM4; SB0;
        BAR; SB0;

        #pragma unroll 1
        for (int t = 0; t < nst; ++t) {
            const int r_ = t % 3;
            if (t + 2 < nst) { const int rn_ = (t + 2) % 3; PV_STAGE(t + 2, rn_) }
            SB0;
            PV_BODY(r_)
            LGKM0; SB0;
            if (t + 2 < nst)      { VM4; SB0; }
            else if (t + 1 < nst) { VM0; SB0; }
            if (t + 1 < nst) { BAR; SB0; }
        }

        #pragma unroll
        for (int mf = 0; mf < 4; ++mf) {
            float ilv[4];
            #pragma unroll
            for (int rr = 0; rr < 4; ++rr)
                ilv[rr] = il[(size_t)b * S_ + q0 + wm * 64 + mf * 16 + quad * 4 + rr];
            #pragma unroll
            for (int nf = 0; nf < 4; ++nf)
                #pragma unroll
                for (int rr = 0; rr < 4; ++rr) {
                    int rowq = q0 + wm * 64 + mf * 16 + quad * 4 + rr;
                    int col = d0 + wn * 64 + nf * 16 + ln;
                    O[((size_t)b * S_ + rowq) * D_ + col] = acc[mf][nf][rr] * ilv[rr];
                }
        }
    }
#undef PV_STAGE
#undef PV_BODY
}

extern "C" void kernel_launch(void* const* d_in, const int* in_sizes, int n_in,
                              void* d_out, int out_size, void* d_ws, size_t ws_size,
                              hipStream_t stream) {
    const float* x  = (const float*)d_in[0];
    const float* Wq = (const float*)d_in[1];
    const float* Wk = (const float*)d_in[2];
    const float* Wv = (const float*)d_in[3];

    const size_t nQ = (size_t)B_ * S_ * D_;
    const size_t nP = (size_t)B_ * PAIRS_ * 128 * 128;

    unsigned short* P  = (unsigned short*)d_ws;
    unsigned short* xb = P;                       // alias: dead before P written
    unsigned short* Q  = P + nP;
    unsigned short* K  = Q + nQ;
    unsigned short* Vt = K + nQ;
    unsigned short* Wt = Vt + nQ;
    float* lpart = (float*)(Wt + (size_t)3 * D_ * D_);
    float* il    = lpart + (size_t)B_ * PAIRS_ * 128;
    float* O = (float*)d_out;

    hipLaunchKernelGGL(prep_x, dim3(8192), dim3(256), 0, stream, x, xb);
    hipLaunchKernelGGL(prep_w, dim3(16, 16, 3), dim3(256), 0, stream, Wq, Wk, Wv, Wt);
    hipLaunchKernelGGL(qkv_gemm, dim3(256, 1, 3), dim3(512), 0, stream, xb, Wt, Q, K, Vt);
    hipLaunchKernelGGL(qk_pexp, dim3(272, B_), dim3(256), 0, stream, Q, K, P, lpart);
    hipLaunchKernelGGL(merge_il, dim3(NT_, B_), dim3(128), 0, stream, lpart, il);
    hipLaunchKernelGGL(pv_gemm, dim3(512), dim3(256), 0, stream, P, Vt, il, O);
}